// Round 6
// baseline (9611.018 us; speedup 1.0000x reference)
//
#include <hip/hip_runtime.h>
#include <hip/hip_fp16.h>

// RNN_14078902797083: 2-layer tanh RNN + FC + softmax, fp32 in/out.
// B=64, T=2048, IN=256, H=512, NCLASS=2.
//
// R10: back to single-WG-per-batch (R9's row-split proved per-step cross-WG
// exchange costs ~1.5us RT regardless of poll footprint — latency-poisoned).
// Fix the R7 scan's real bottleneck (DS-instruction-bound: 44 b128/thread):
// h distributed via ONE uint4 lane-spread read per wave (lane c holds h-uints
// 4c..4c+3, so chunk c = readlane lane c — full 256-uint coverage, correct
// mapping; R7's uint2 variant only covered uints 0..127) + 16 uniform
// broadcast chunks to offload VALU. DS 44->34 instr/thread/step. Weight
// split unchanged vs R7 (48 reg-chunks + 16 LDS-chunks) to isolate the
// h-path variable. One barrier/step, parity-double-buffered h.

#define BB 64
#define TT 2048
#define IN 256
#define HH 512
#define MM (BB * TT)          // 131072 rows

// workspace layout (bytes)
#define BUF0_OFF 0ull                      // [B][T][H] f32 = 256 MB (xw0 -> h1 -> xw1, in place)
#define WT_OFF   268435456ull              // W^T scratch, 1 MB
#define H2L_OFF  269484032ull              // [B][H] f32 last hidden = 128 KB

// ---- recurrent weight split ----
#define NCHR 48                  // uint4 weight chunks in VGPR/AGPR (k = 0..383)
#define NCHL 16                  // uint4 weight chunks in LDS      (k = 384..511)
#define NB   16                  // h-chunks via LDS uniform broadcast (rest via readlane)
#define SCAN_SMEM (NCHL * HH * 16 + 2 * 256 * 4)   // 131072 + 2048 = 133120 B

typedef _Float16 v2h __attribute__((ext_vector_type(2)));

__device__ __forceinline__ float fdot2u(unsigned a, unsigned b, float c) {
#if __has_builtin(__builtin_amdgcn_fdot2)
    union { unsigned u; v2h h; } ua, ub;
    ua.u = a; ub.u = b;
    return __builtin_amdgcn_fdot2(ua.h, ub.h, c, false);
#else
    __half2 ah = *reinterpret_cast<__half2*>(&a);
    __half2 bh = *reinterpret_cast<__half2*>(&b);
    float2 fa = __half22float2(ah), fb = __half22float2(bh);
    return fmaf(fa.y, fb.y, fmaf(fa.x, fb.x, c));
#endif
}

__device__ __forceinline__ unsigned pk2(float x, float y) {
    unsigned lo = (unsigned)__half_as_ushort(__float2half(x));
    unsigned hi = (unsigned)__half_as_ushort(__float2half(y));
    return lo | (hi << 16);
}

__device__ __forceinline__ unsigned rdlane(unsigned v, int lane) {
    return (unsigned)__builtin_amdgcn_readlane((int)v, lane);
}

// fast tanh: copysign((1-e)/(1+e), x), e = exp(-2|x|). No overflow; ~2e-6 abs err.
__device__ __forceinline__ float fast_tanh(float x) {
    const float ax = __builtin_fabsf(x);
    const float e  = __expf(-2.f * ax);
    const float r  = (1.f - e) * __builtin_amdgcn_rcpf(1.f + e);
    return __builtin_copysignf(r, x);
}

// -------------------- W transpose: W[512][K] -> WT[K][512] --------------------
__global__ void transpose_w(const float* __restrict__ W, float* __restrict__ WT, int K)
{
    __shared__ float tile[32][33];
    const int k0 = blockIdx.x * 32;
    const int c0 = blockIdx.y * 32;
    const int tx = threadIdx.x & 31;
    const int ty = threadIdx.x >> 5;          // 0..7
    #pragma unroll
    for (int i = ty; i < 32; i += 8)
        tile[i][tx] = W[(size_t)(c0 + i) * K + k0 + tx];   // coalesced along k
    __syncthreads();
    #pragma unroll
    for (int i = ty; i < 32; i += 8)
        WT[(size_t)(k0 + i) * HH + c0 + tx] = tile[tx][i]; // coalesced along c
}

// -------------------- input projection GEMM: out = A @ W^T + (b1+b2) ----------
// A [M][K] (may alias out), WT [K][512], out [M][512]. 32 rows/WG, full N.
// Full-K A staging in LDS BEFORE any write -> in-place safe per 32-row block.
template <int K>
__global__ __launch_bounds__(256, 2)
void gemm_xw(const float* A, const float* __restrict__ WT,
             const float* __restrict__ b1, const float* __restrict__ b2,
             float* out)
{
    extern __shared__ char smem[];
    float* As = (float*)smem;                 // [32][K]
    const int m0 = blockIdx.x * 32;
    const int tid = threadIdx.x;

    const float* Ab = A + (size_t)m0 * K;
    #pragma unroll
    for (int i = 0; i < (32 * K) / 1024; ++i) {
        const int idx = tid * 4 + i * 1024;
        *(float4*)&As[idx] = *(const float4*)&Ab[idx];
    }
    __syncthreads();

    const int tc = tid & 63;                  // col base lane; cols c = tc + 64*cc
    const int r0 = (tid >> 6) * 8;            // 8 rows per thread

    float acc[8][8];
    #pragma unroll
    for (int cc = 0; cc < 8; ++cc) {
        const int c = tc + 64 * cc;
        const float bb = b1[c] + b2[c];
        #pragma unroll
        for (int rr = 0; rr < 8; ++rr) acc[rr][cc] = bb;
    }

    #pragma unroll 2
    for (int k = 0; k < K; k += 4) {
        float4 av4[8];
        #pragma unroll
        for (int rr = 0; rr < 8; ++rr)
            av4[rr] = *(const float4*)&As[(r0 + rr) * K + k];   // wave-uniform: broadcast
        #pragma unroll
        for (int kk = 0; kk < 4; ++kk) {
            float wv[8];
            #pragma unroll
            for (int cc = 0; cc < 8; ++cc)
                wv[cc] = WT[(size_t)(k + kk) * HH + tc + 64 * cc];  // lane-consecutive: coalesced
            #pragma unroll
            for (int rr = 0; rr < 8; ++rr) {
                const float a = ((const float*)&av4[rr])[kk];
                #pragma unroll
                for (int cc = 0; cc < 8; ++cc)
                    acc[rr][cc] = fmaf(a, wv[cc], acc[rr][cc]);
            }
        }
    }

    #pragma unroll
    for (int rr = 0; rr < 8; ++rr) {
        float* orow = out + (size_t)(m0 + r0 + rr) * HH;
        #pragma unroll
        for (int cc = 0; cc < 8; ++cc)
            orow[tc + 64 * cc] = acc[rr][cc];
    }
}

// -------------------- recurrent scan: one WG per batch, no inter-WG comm ------
// Thread j owns full row j. h_{t-1} (256 packed uints) reaches each thread as:
//   chunks 0..NB-1   : uniform LDS uint4 broadcast
//   chunks NB..63    : readlane from ONE lane-spread uint4 (lane c = uints 4c..4c+3)
template <bool WRITE_SEQ>
__global__ __launch_bounds__(512, 2)
void scan_rnn(const float* xw,                 // [B][T][H]; aliased by hseq when WRITE_SEQ
              const float* __restrict__ Whh,   // [H][H]
              float* hseq)                     // WRITE_SEQ: [B][T][H] (alias of xw); else [B][H]
{
    extern __shared__ char smem[];
    uint4*    wlds4 = (uint4*)smem;                             // [NCHL][HH]
    unsigned* hpk   = (unsigned*)(smem + NCHL * HH * 16);       // [2][256] packed fp16 h

    const int b = blockIdx.x;
    const int j = threadIdx.x;                 // output row 0..511
    const int l = j & 63;                      // lane

    // ---- one-time: W_hh row j -> 48 reg chunks + 16 LDS chunks (fp16) ----
    const float* wrow = Whh + (size_t)j * HH;
    uint4 w4[NCHR];
    #pragma unroll
    for (int c = 0; c < NCHR; ++c) {
        const float4 f0 = *(const float4*)(wrow + c * 8);
        const float4 f1 = *(const float4*)(wrow + c * 8 + 4);
        w4[c].x = pk2(f0.x, f0.y); w4[c].y = pk2(f0.z, f0.w);
        w4[c].z = pk2(f1.x, f1.y); w4[c].w = pk2(f1.z, f1.w);
    }
    #pragma unroll
    for (int cc = 0; cc < NCHL; ++cc) {
        const float* p = wrow + NCHR * 8 + cc * 8;
        const float4 f0 = *(const float4*)(p);
        const float4 f1 = *(const float4*)(p + 4);
        uint4 v;
        v.x = pk2(f0.x, f0.y); v.y = pk2(f0.z, f0.w);
        v.z = pk2(f1.x, f1.y); v.w = pk2(f1.z, f1.w);
        wlds4[cc * HH + j] = v;                // lane-consecutive: conflict-free
    }
    __syncthreads();

    const float* xrow = xw + (size_t)b * TT * HH + j;
    float* srow = WRITE_SEQ ? (hseq + (size_t)b * TT * HH + j) : nullptr;

    float xw_cur = xrow[0];
    float xw_n1  = xrow[HH];
    for (int t = 0; t < TT; ++t) {
        const int t2 = (t + 2 < TT) ? (t + 2) : (TT - 1);
        const float xw_n2 = xrow[(size_t)t2 * HH];       // 2-deep prefetch

        float z = xw_cur;
        if (t > 0) {
            const unsigned* hp = hpk + (((t & 1) ^ 1) * 256);   // parity (t-1)&1
            // ONE lane-spread b128: lane c holds h-uints 4c..4c+3
            const uint4 hv = *(const uint4*)(hp + 4 * l);
            float a0 = 0.f, a1 = 0.f, a2 = 0.f, a3 = 0.f;
            // chunks 0..NB-1: uniform broadcast h, reg weights
            #pragma unroll
            for (int c = 0; c < NB; ++c) {
                const uint4 hb = *(const uint4*)(hp + 4 * c);
                a0 = fdot2u(w4[c].x, hb.x, a0);
                a1 = fdot2u(w4[c].y, hb.y, a1);
                a2 = fdot2u(w4[c].z, hb.z, a2);
                a3 = fdot2u(w4[c].w, hb.w, a3);
            }
            // chunks NB..NCHR-1: readlane h (chunk c = lane c), reg weights
            #pragma unroll
            for (int c = NB; c < NCHR; ++c) {
                const unsigned s0 = rdlane(hv.x, c);
                const unsigned s1 = rdlane(hv.y, c);
                const unsigned s2 = rdlane(hv.z, c);
                const unsigned s3 = rdlane(hv.w, c);
                a0 = fdot2u(w4[c].x, s0, a0);
                a1 = fdot2u(w4[c].y, s1, a1);
                a2 = fdot2u(w4[c].z, s2, a2);
                a3 = fdot2u(w4[c].w, s3, a3);
            }
            // chunks NCHR..63: readlane h, LDS weights (lane-consecutive)
            #pragma unroll
            for (int cc = 0; cc < NCHL; ++cc) {
                const int c = NCHR + cc;
                const uint4 wv = wlds4[cc * HH + j];
                const unsigned s0 = rdlane(hv.x, c);
                const unsigned s1 = rdlane(hv.y, c);
                const unsigned s2 = rdlane(hv.z, c);
                const unsigned s3 = rdlane(hv.w, c);
                a0 = fdot2u(wv.x, s0, a0);
                a1 = fdot2u(wv.y, s1, a1);
                a2 = fdot2u(wv.z, s2, a2);
                a3 = fdot2u(wv.w, s3, a3);
            }
            z += (a0 + a1) + (a2 + a3);
        }
        const float h = fast_tanh(z);

        // publish h_t into parity t&1 (read next step); one barrier per step
        ((unsigned short*)(hpk + (t & 1) * 256))[j] = __half_as_ushort(__float2half(h));

        if (WRITE_SEQ) {
            srow[(size_t)t * HH] = h;          // in-place over xw[b][t][j]: thread-local element
        } else if (t == TT - 1) {
            hseq[b * HH + j] = h;
        }
        xw_cur = xw_n1;
        xw_n1  = xw_n2;
        __syncthreads();
    }
}

// -------------------- FC + softmax --------------------
__global__ void fc_kernel(const float* __restrict__ h2, const float* __restrict__ w,
                          const float* __restrict__ bvec, float* __restrict__ out)
{
    const int b = threadIdx.x;   // 64 threads
    float z0 = bvec[0], z1 = bvec[1];
    #pragma unroll 4
    for (int k = 0; k < HH; k += 4) {
        float4 h  = *(const float4*)&h2[b * HH + k];
        float4 w0 = *(const float4*)&w[k];
        float4 w1 = *(const float4*)&w[HH + k];
        z0 += h.x * w0.x + h.y * w0.y + h.z * w0.z + h.w * w0.w;
        z1 += h.x * w1.x + h.y * w1.y + h.z * w1.z + h.w * w1.w;
    }
    const float m  = fmaxf(z0, z1);
    const float e0 = expf(z0 - m), e1 = expf(z1 - m);
    const float inv = 1.f / (e0 + e1);
    out[b * 2 + 0] = e0 * inv;
    out[b * 2 + 1] = e1 * inv;
}

extern "C" void kernel_launch(void* const* d_in, const int* in_sizes, int n_in,
                              void* d_out, int out_size, void* d_ws, size_t ws_size,
                              hipStream_t stream)
{
    (void)in_sizes; (void)n_in; (void)out_size; (void)ws_size;
    const float* x    = (const float*)d_in[0];
    const float* Wih0 = (const float*)d_in[1];
    const float* Whh0 = (const float*)d_in[2];
    const float* bih0 = (const float*)d_in[3];
    const float* bhh0 = (const float*)d_in[4];
    const float* Wih1 = (const float*)d_in[5];
    const float* Whh1 = (const float*)d_in[6];
    const float* bih1 = (const float*)d_in[7];
    const float* bhh1 = (const float*)d_in[8];
    const float* fcw  = (const float*)d_in[9];
    const float* fcb  = (const float*)d_in[10];
    float* out = (float*)d_out;

    char* ws = (char*)d_ws;
    float* buf0 = (float*)(ws + BUF0_OFF);
    float* WT   = (float*)(ws + WT_OFF);
    float* h2l  = (float*)(ws + H2L_OFF);

    static bool attr_done = false;
    if (!attr_done) {
        (void)hipFuncSetAttribute((const void*)scan_rnn<true>,
                                  hipFuncAttributeMaxDynamicSharedMemorySize, SCAN_SMEM);
        (void)hipFuncSetAttribute((const void*)scan_rnn<false>,
                                  hipFuncAttributeMaxDynamicSharedMemorySize, SCAN_SMEM);
        attr_done = true;
    }

    // ---- layer 0 ----
    transpose_w<<<dim3(IN / 32, HH / 32), dim3(256), 0, stream>>>(Wih0, WT, IN);
    gemm_xw<IN><<<dim3(MM / 32), dim3(256), 32 * IN * 4, stream>>>(x, WT, bih0, bhh0, buf0);
    scan_rnn<true><<<dim3(BB), dim3(512), SCAN_SMEM, stream>>>(buf0, Whh0, buf0);

    // ---- layer 1 (WT buffer reused: lifetimes disjoint) ----
    transpose_w<<<dim3(HH / 32, HH / 32), dim3(256), 0, stream>>>(Wih1, WT, HH);
    gemm_xw<HH><<<dim3(MM / 32), dim3(256), 32 * HH * 4, stream>>>(buf0, WT, bih1, bhh1, buf0);
    scan_rnn<false><<<dim3(BB), dim3(512), SCAN_SMEM, stream>>>(buf0, Whh1, h2l);

    // ---- FC + softmax ----
    fc_kernel<<<dim3(1), dim3(64), 0, stream>>>(h2l, fcw, fcb, out);
}

// Round 7
// 6186.443 us; speedup vs baseline: 1.5536x; 1.5536x over previous
//
#include <hip/hip_runtime.h>
#include <hip/hip_fp16.h>

// RNN_14078902797083: 2-layer tanh RNN + FC + softmax, fp32 in/out.
// B=64, T=2048, IN=256, H=512, NCLASS=2.
//
// R11: int8 recurrence. R5/R7/R10 established the scan is DS-issue-bound
// (~640 DS instr/step/CU ~ 3900 cyc): fp16 W doesn't fit the 512KB/CU reg
// file (forces a 128KB LDS quarter = 16 b128/thread/step) and fp16 h costs
// 64 uniform b128/thread/step. Int8 fixes both: full W row = 128 dwords in
// REGISTERS (no weight LDS traffic, no k-split, no reduction), h packed
// int8 = 32 uniform b128/thread/step, v_dot4_i32_i8 = 128 dot4/thread/step.
// Per-row weight scale max|row|/127, h scale 1/127 (|tanh|<1), fp32 xw and
// accumulate-combine. DS/step/CU: 640 -> 264 instrs. One barrier/step.

#define BB 64
#define TT 2048
#define IN 256
#define HH 512
#define MM (BB * TT)          // 131072 rows

// workspace layout (bytes)
#define BUF0_OFF 0ull                      // [B][T][H] f32 = 256 MB (xw0 -> h1 -> xw1, in place)
#define WT_OFF   268435456ull              // W^T scratch, 1 MB
#define H2L_OFF  269484032ull              // [B][H] f32 last hidden = 128 KB

__device__ __forceinline__ int sd4(unsigned a, unsigned b, int c) {
#if __has_builtin(__builtin_amdgcn_sdot4)
    return __builtin_amdgcn_sdot4((int)a, (int)b, c, false);
#else
    const int a0 = (int)(char)(a), a1 = (int)(char)(a >> 8);
    const int a2 = (int)(char)(a >> 16), a3 = (int)(char)(a >> 24);
    const int b0 = (int)(char)(b), b1 = (int)(char)(b >> 8);
    const int b2 = (int)(char)(b >> 16), b3 = (int)(char)(b >> 24);
    return c + a0 * b0 + a1 * b1 + a2 * b2 + a3 * b3;
#endif
}

// fast tanh: copysign((1-e)/(1+e), x), e = exp(-2|x|). No overflow; ~2e-6 abs err.
__device__ __forceinline__ float fast_tanh(float x) {
    const float ax = __builtin_fabsf(x);
    const float e  = __expf(-2.f * ax);
    const float r  = (1.f - e) * __builtin_amdgcn_rcpf(1.f + e);
    return __builtin_copysignf(r, x);
}

__device__ __forceinline__ unsigned pkq4(float s, float x0, float x1, float x2, float x3) {
    // quantize 4 floats by scale s and pack as 4 int8
    const int q0 = (int)rintf(x0 * s), q1 = (int)rintf(x1 * s);
    const int q2 = (int)rintf(x2 * s), q3 = (int)rintf(x3 * s);
    return (unsigned)(q0 & 0xFF) | ((unsigned)(q1 & 0xFF) << 8) |
           ((unsigned)(q2 & 0xFF) << 16) | ((unsigned)(q3 & 0xFF) << 24);
}

// -------------------- W transpose: W[512][K] -> WT[K][512] --------------------
__global__ void transpose_w(const float* __restrict__ W, float* __restrict__ WT, int K)
{
    __shared__ float tile[32][33];
    const int k0 = blockIdx.x * 32;
    const int c0 = blockIdx.y * 32;
    const int tx = threadIdx.x & 31;
    const int ty = threadIdx.x >> 5;          // 0..7
    #pragma unroll
    for (int i = ty; i < 32; i += 8)
        tile[i][tx] = W[(size_t)(c0 + i) * K + k0 + tx];   // coalesced along k
    __syncthreads();
    #pragma unroll
    for (int i = ty; i < 32; i += 8)
        WT[(size_t)(k0 + i) * HH + c0 + tx] = tile[tx][i]; // coalesced along c
}

// -------------------- input projection GEMM: out = A @ W^T + (b1+b2) ----------
// A [M][K] (may alias out), WT [K][512], out [M][512]. 32 rows/WG, full N.
// Full-K A staging in LDS BEFORE any write -> in-place safe per 32-row block.
template <int K>
__global__ __launch_bounds__(256, 2)
void gemm_xw(const float* A, const float* __restrict__ WT,
             const float* __restrict__ b1, const float* __restrict__ b2,
             float* out)
{
    extern __shared__ char smem[];
    float* As = (float*)smem;                 // [32][K]
    const int m0 = blockIdx.x * 32;
    const int tid = threadIdx.x;

    const float* Ab = A + (size_t)m0 * K;
    #pragma unroll
    for (int i = 0; i < (32 * K) / 1024; ++i) {
        const int idx = tid * 4 + i * 1024;
        *(float4*)&As[idx] = *(const float4*)&Ab[idx];
    }
    __syncthreads();

    const int tc = tid & 63;                  // col base lane; cols c = tc + 64*cc
    const int r0 = (tid >> 6) * 8;            // 8 rows per thread

    float acc[8][8];
    #pragma unroll
    for (int cc = 0; cc < 8; ++cc) {
        const int c = tc + 64 * cc;
        const float bb = b1[c] + b2[c];
        #pragma unroll
        for (int rr = 0; rr < 8; ++rr) acc[rr][cc] = bb;
    }

    #pragma unroll 2
    for (int k = 0; k < K; k += 4) {
        float4 av4[8];
        #pragma unroll
        for (int rr = 0; rr < 8; ++rr)
            av4[rr] = *(const float4*)&As[(r0 + rr) * K + k];   // wave-uniform: broadcast
        #pragma unroll
        for (int kk = 0; kk < 4; ++kk) {
            float wv[8];
            #pragma unroll
            for (int cc = 0; cc < 8; ++cc)
                wv[cc] = WT[(size_t)(k + kk) * HH + tc + 64 * cc];  // lane-consecutive: coalesced
            #pragma unroll
            for (int rr = 0; rr < 8; ++rr) {
                const float a = ((const float*)&av4[rr])[kk];
                #pragma unroll
                for (int cc = 0; cc < 8; ++cc)
                    acc[rr][cc] = fmaf(a, wv[cc], acc[rr][cc]);
            }
        }
    }

    #pragma unroll
    for (int rr = 0; rr < 8; ++rr) {
        float* orow = out + (size_t)(m0 + r0 + rr) * HH;
        #pragma unroll
        for (int cc = 0; cc < 8; ++cc)
            orow[tc + 64 * cc] = acc[rr][cc];
    }
}

// -------------------- recurrent scan: one WG per batch, int8 dot4 -------------
// Thread j owns full row j: 128 int8-packed weight dwords in REGISTERS.
// h_{t-1}: 512 int8 in LDS, read as 32 uniform uint4 broadcasts/thread.
template <bool WRITE_SEQ>
__global__ __launch_bounds__(512, 2)
void scan_rnn(const float* xw,                 // [B][T][H]; aliased by hseq when WRITE_SEQ
              const float* __restrict__ Whh,   // [H][H]
              float* hseq)                     // WRITE_SEQ: [B][T][H] (alias of xw); else [B][H]
{
    __shared__ alignas(16) unsigned hq[2][128];   // [parity][512 int8]

    const int b = blockIdx.x;
    const int j = threadIdx.x;                 // output row 0..511

    // ---- one-time: quantize W_hh row j to int8, keep in registers ----
    const float* wrow = Whh + (size_t)j * HH;
    float mx = 1e-20f;
    #pragma unroll
    for (int c = 0; c < 128; ++c) {
        const float4 f = *(const float4*)(wrow + 4 * c);
        mx = fmaxf(mx, fmaxf(fmaxf(__builtin_fabsf(f.x), __builtin_fabsf(f.y)),
                             fmaxf(__builtin_fabsf(f.z), __builtin_fabsf(f.w))));
    }
    const float inv_sw = 127.f / mx;
    const float scale  = mx / 16129.f;         // (mx/127)/127
    unsigned w8[128];
    #pragma unroll
    for (int c = 0; c < 128; ++c) {
        const float4 f = *(const float4*)(wrow + 4 * c);
        w8[c] = pkq4(inv_sw, f.x, f.y, f.z, f.w);
    }

    const float* xrow = xw + (size_t)b * TT * HH + j;
    float* srow = WRITE_SEQ ? (hseq + (size_t)b * TT * HH + j) : nullptr;

    float xw_cur = xrow[0];
    float xw_n1  = xrow[HH];
    for (int t = 0; t < TT; ++t) {
        const int t2 = (t + 2 < TT) ? (t + 2) : (TT - 1);
        const float xw_n2 = xrow[(size_t)t2 * HH];       // 2-deep prefetch

        float z = xw_cur;
        if (t > 0) {
            const unsigned* hp = hq[(t & 1) ^ 1];        // parity (t-1)&1
            int acc = 0;
            #pragma unroll
            for (int c = 0; c < 32; ++c) {
                const uint4 hb = *(const uint4*)(hp + 4 * c);   // uniform: LDS broadcast
                acc = sd4(w8[4 * c + 0], hb.x, acc);
                acc = sd4(w8[4 * c + 1], hb.y, acc);
                acc = sd4(w8[4 * c + 2], hb.z, acc);
                acc = sd4(w8[4 * c + 3], hb.w, acc);
            }
            z += (float)acc * scale;
        }
        const float h = fast_tanh(z);

        // quantize + publish h_t into parity t&1 (clamp guards rcp overshoot)
        const float qf = fminf(fmaxf(h * 127.f, -127.f), 127.f);
        const int   qi = (int)rintf(qf);
        ((char*)hq[t & 1])[j] = (char)qi;

        if (WRITE_SEQ) {
            srow[(size_t)t * HH] = h;          // in-place over xw[b][t][j]: thread-local element
        } else if (t == TT - 1) {
            hseq[b * HH + j] = h;
        }
        xw_cur = xw_n1;
        xw_n1  = xw_n2;
        __syncthreads();
    }
}

// -------------------- FC + softmax --------------------
__global__ void fc_kernel(const float* __restrict__ h2, const float* __restrict__ w,
                          const float* __restrict__ bvec, float* __restrict__ out)
{
    const int b = threadIdx.x;   // 64 threads
    float z0 = bvec[0], z1 = bvec[1];
    #pragma unroll 4
    for (int k = 0; k < HH; k += 4) {
        float4 h  = *(const float4*)&h2[b * HH + k];
        float4 w0 = *(const float4*)&w[k];
        float4 w1 = *(const float4*)&w[HH + k];
        z0 += h.x * w0.x + h.y * w0.y + h.z * w0.z + h.w * w0.w;
        z1 += h.x * w1.x + h.y * w1.y + h.z * w1.z + h.w * w1.w;
    }
    const float m  = fmaxf(z0, z1);
    const float e0 = expf(z0 - m), e1 = expf(z1 - m);
    const float inv = 1.f / (e0 + e1);
    out[b * 2 + 0] = e0 * inv;
    out[b * 2 + 1] = e1 * inv;
}

extern "C" void kernel_launch(void* const* d_in, const int* in_sizes, int n_in,
                              void* d_out, int out_size, void* d_ws, size_t ws_size,
                              hipStream_t stream)
{
    (void)in_sizes; (void)n_in; (void)out_size; (void)ws_size;
    const float* x    = (const float*)d_in[0];
    const float* Wih0 = (const float*)d_in[1];
    const float* Whh0 = (const float*)d_in[2];
    const float* bih0 = (const float*)d_in[3];
    const float* bhh0 = (const float*)d_in[4];
    const float* Wih1 = (const float*)d_in[5];
    const float* Whh1 = (const float*)d_in[6];
    const float* bih1 = (const float*)d_in[7];
    const float* bhh1 = (const float*)d_in[8];
    const float* fcw  = (const float*)d_in[9];
    const float* fcb  = (const float*)d_in[10];
    float* out = (float*)d_out;

    char* ws = (char*)d_ws;
    float* buf0 = (float*)(ws + BUF0_OFF);
    float* WT   = (float*)(ws + WT_OFF);
    float* h2l  = (float*)(ws + H2L_OFF);

    // ---- layer 0 ----
    transpose_w<<<dim3(IN / 32, HH / 32), dim3(256), 0, stream>>>(Wih0, WT, IN);
    gemm_xw<IN><<<dim3(MM / 32), dim3(256), 32 * IN * 4, stream>>>(x, WT, bih0, bhh0, buf0);
    scan_rnn<true><<<dim3(BB), dim3(512), 0, stream>>>(buf0, Whh0, buf0);

    // ---- layer 1 (WT buffer reused: lifetimes disjoint) ----
    transpose_w<<<dim3(HH / 32, HH / 32), dim3(256), 0, stream>>>(Wih1, WT, HH);
    gemm_xw<HH><<<dim3(MM / 32), dim3(256), 32 * HH * 4, stream>>>(buf0, WT, bih1, bhh1, buf0);
    scan_rnn<false><<<dim3(BB), dim3(512), 0, stream>>>(buf0, Whh1, h2l);

    // ---- FC + softmax ----
    fc_kernel<<<dim3(1), dim3(64), 0, stream>>>(h2l, fcw, fcb, out);
}